// Round 4
// baseline (382.482 us; speedup 1.0000x reference)
//
#include <hip/hip_runtime.h>
#include <math.h>

#define DF 512

typedef __attribute__((ext_vector_type(8))) short bf16x8;
typedef __attribute__((ext_vector_type(4))) float f32x4;
typedef __attribute__((ext_vector_type(4))) int int4v;

__device__ __constant__ int c_lidx[16] = {0,1,1,1,2,2,2,2,2,3,3,3,3,3,3,3};

__device__ inline float bf2f(unsigned short s) {
    union { unsigned int u; float f; } x;
    x.u = ((unsigned int)s) << 16;
    return x.f;
}
__device__ inline unsigned short f2bf(float f) {
    union { float f; unsigned int u; } x; x.f = f;
    unsigned int r = x.u + 0x7fffu + ((x.u >> 16) & 1u);
    return (unsigned short)(r >> 16);
}

// K1: per-edge spherical harmonics Y[E][16], fused dst-histogram + src yacc atomics
__global__ void k_edge_sh(const float* __restrict__ pos,
                          const int* __restrict__ src,
                          const int* __restrict__ dst,
                          const float* __restrict__ cell,
                          float* __restrict__ Y,
                          float* __restrict__ yacc,
                          int* __restrict__ cnt, int E)
{
    int e = blockIdx.x * blockDim.x + threadIdx.x;
    if (e >= E) return;
    int s = src[e], d = dst[e];
    float cx = cell[0], cy = cell[4], cz = cell[8];
    float ex = pos[d*3+0] - pos[s*3+0];
    float ey = pos[d*3+1] - pos[s*3+1];
    float ez = pos[d*3+2] - pos[s*3+2];
    ex -= rintf(ex/cx)*cx;
    ey -= rintf(ey/cy)*cy;
    ez -= rintf(ez/cz)*cz;
    float len = fmaxf(sqrtf(ex*ex + ey*ey + ez*ez), 1e-8f);
    float x = ex/len, y = ey/len, z = ez/len;
    float x2 = x*x, y2 = y*y, z2 = z*z;
    float o[16];
    o[0]  = 0.28209479177387814f;
    o[1]  = 0.4886025119029199f*y;
    o[2]  = 0.4886025119029199f*z;
    o[3]  = 0.4886025119029199f*x;
    o[4]  = 1.0925484305920792f*x*y;
    o[5]  = 1.0925484305920792f*y*z;
    o[6]  = 0.31539156525252005f*(3.0f*z2 - 1.0f);
    o[7]  = 1.0925484305920792f*x*z;
    o[8]  = 0.5462742152960396f*(x2 - y2);
    o[9]  = 0.5900435899266435f*y*(3.0f*x2 - y2);
    o[10] = 2.890611442640554f*x*y*z;
    o[11] = 0.4570457994644658f*y*(5.0f*z2 - 1.0f);
    o[12] = 0.3731763325901154f*z*(5.0f*z2 - 3.0f);
    o[13] = 0.4570457994644658f*x*(5.0f*z2 - 1.0f);
    o[14] = 1.445305721320277f*z*(x2 - y2);
    o[15] = 0.5900435899266435f*x*(x2 - 3.0f*y2);
    float4* Yo = (float4*)(Y + (size_t)e*16);
    Yo[0] = make_float4(o[0],o[1],o[2],o[3]);
    Yo[1] = make_float4(o[4],o[5],o[6],o[7]);
    Yo[2] = make_float4(o[8],o[9],o[10],o[11]);
    Yo[3] = make_float4(o[12],o[13],o[14],o[15]);
    float* yr = yacc + (size_t)s*16;
    #pragma unroll
    for (int m = 0; m < 16; m++) atomicAdd(&yr[m], o[m]);
    atomicAdd(&cnt[d], 1);
}

// K2: per-ELEMENT tensor-product: tfe[a, d*16+m] = bf16( sum_c emb[a][c*16+m] * W0[l(m)][c][d] )
__global__ __launch_bounds__(256) void k_tf_elem(const float* __restrict__ emb,
                                                 const float* __restrict__ w0,
                                                 unsigned short* __restrict__ tfe, int NE)
{
    __shared__ float nf[DF];
    __shared__ float w[4*32*32];
    int a = blockIdx.x;
    int t = threadIdx.x;
    nf[t]       = emb[(size_t)a*DF + t];
    nf[t + 256] = emb[(size_t)a*DF + t + 256];
    for (int i = t; i < 4096; i += 256) w[i] = w0[i];
    __syncthreads();
    #pragma unroll
    for (int rep = 0; rep < 2; rep++) {
        int f = t + rep*256;
        int d = f >> 4, m = f & 15;
        int l = c_lidx[m];
        const float* wl = &w[l*1024 + d];
        float acc = 0.0f;
        #pragma unroll
        for (int c = 0; c < 32; c++) acc += nf[c*16 + m] * wl[c*32];
        tfe[(size_t)a*DF + f] = f2bf(acc);
    }
}

// single-block exclusive scan (4 elems/thread): cnt[0..N) -> rp[0..N]; cnt becomes cursor
__global__ __launch_bounds__(1024) void k_scan(int* __restrict__ cnt,
                                               int* __restrict__ rp, int N, int E)
{
    __shared__ int wsum[16];
    __shared__ int sh_total;
    __shared__ int sh_carry;
    int t = threadIdx.x;
    int lane = t & 63, wv = t >> 6;
    if (t == 0) sh_carry = 0;
    __syncthreads();
    for (int base = 0; base < N; base += 4096) {
        int i0 = base + t*4;
        int v0 = (i0+0 < N) ? cnt[i0+0] : 0;
        int v1 = (i0+1 < N) ? cnt[i0+1] : 0;
        int v2 = (i0+2 < N) ? cnt[i0+2] : 0;
        int v3 = (i0+3 < N) ? cnt[i0+3] : 0;
        int s0 = v0, s1 = s0+v1, s2 = s1+v2, tot = s2+v3;
        int v = tot;
        #pragma unroll
        for (int off = 1; off < 64; off <<= 1) {
            int x = __shfl_up(v, off, 64);
            if (lane >= off) v += x;
        }
        if (lane == 63) wsum[wv] = v;
        __syncthreads();
        if (t < 16) {
            int x = wsum[t];
            int incl = x;
            #pragma unroll
            for (int off = 1; off < 16; off <<= 1) {
                int y = __shfl_up(incl, off, 16);
                if (t >= off) incl += y;
            }
            wsum[t] = incl - x;
            if (t == 15) sh_total = incl;
        }
        __syncthreads();
        int excl = sh_carry + wsum[wv] + (v - tot);
        if (i0+0 < N) { rp[i0+0] = excl;      cnt[i0+0] = excl; }
        if (i0+1 < N) { rp[i0+1] = excl + s0; cnt[i0+1] = excl + s0; }
        if (i0+2 < N) { rp[i0+2] = excl + s1; cnt[i0+2] = excl + s1; }
        if (i0+3 < N) { rp[i0+3] = excl + s2; cnt[i0+3] = excl + s2; }
        __syncthreads();
        if (t == 0) sh_carry += sh_total;
        __syncthreads();
    }
    if (t == 0) rp[N] = E;
}

// fill CSR: eA[p] = edge id, aA[p] = element of src node
__global__ void k_fill(const int* __restrict__ src, const int* __restrict__ dst,
                       const int* __restrict__ an,
                       int* __restrict__ cur, int* __restrict__ eA,
                       int* __restrict__ aA, int E)
{
    int e = blockIdx.x * blockDim.x + threadIdx.x;
    if (e >= E) return;
    int d = dst[e];
    int p = atomicAdd(&cur[d], 1);
    eA[p] = e;
    aA[p] = an[src[e]];
}

// K3: CSR aggregation, one wave per destination node.
// aggbf[n, f] = bf16( sum_{edges into n} Y[e, f&15] * tfe[aA, f] )
__device__ inline void agg_edge(const unsigned short* __restrict__ tfe,
                                const float* __restrict__ Y,
                                int e, int a, int f0, int yoff, float* acc)
{
    bf16x8 v = *(const bf16x8*)(tfe + (size_t)a*DF + f0);
    const float4* q = (const float4*)(Y + (size_t)e*16 + yoff);
    float4 y0 = q[0], y1 = q[1];
    acc[0] += bf2f((unsigned short)v[0])*y0.x;
    acc[1] += bf2f((unsigned short)v[1])*y0.y;
    acc[2] += bf2f((unsigned short)v[2])*y0.z;
    acc[3] += bf2f((unsigned short)v[3])*y0.w;
    acc[4] += bf2f((unsigned short)v[4])*y1.x;
    acc[5] += bf2f((unsigned short)v[5])*y1.y;
    acc[6] += bf2f((unsigned short)v[6])*y1.z;
    acc[7] += bf2f((unsigned short)v[7])*y1.w;
}

__global__ __launch_bounds__(256) void k_agg(const unsigned short* __restrict__ tfe,
                                             const float* __restrict__ Y,
                                             const int* __restrict__ rp,
                                             const int* __restrict__ eA,
                                             const int* __restrict__ aA,
                                             unsigned short* __restrict__ aggbf, int N)
{
    int wid = blockIdx.x * 4 + (threadIdx.x >> 6);
    if (wid >= N) return;
    int lane = threadIdx.x & 63;
    int f0 = lane * 8;
    int yoff = f0 & 15;
    int beg = rp[wid], end = rp[wid + 1];
    float acc[8] = {0,0,0,0,0,0,0,0};
    int i = beg;
    for (; i + 1 < end; i += 2) {
        agg_edge(tfe, Y, eA[i],   aA[i],   f0, yoff, acc);
        agg_edge(tfe, Y, eA[i+1], aA[i+1], f0, yoff, acc);
    }
    if (i < end) agg_edge(tfe, Y, eA[i], aA[i], f0, yoff, acc);
    bf16x8 o;
    #pragma unroll
    for (int j = 0; j < 8; j++) o[j] = (short)f2bf(acc[j]);
    *(bf16x8*)(aggbf + (size_t)wid*DF + f0) = o;
}

// Bt[n][k] = bf16(lin_w0[k][n])
__global__ void k_convb(const float* __restrict__ w, unsigned short* __restrict__ bt)
{
    int idx = blockIdx.x * 256 + threadIdx.x;
    int n = idx >> 9, k = idx & 511;
    bt[idx] = f2bf(w[(size_t)k*DF + n]);
}

// K4: MFMA GEMM, fully-fused epilogue:
// out += sum_{row,col} (A@B + emb[an] + bias)[row,col] * (outw[col] + u1[col]*yacc[row,col&15])
#define GBM 128
#define GBN 128
#define GBK 32
#define LDK 40
__global__ __launch_bounds__(256) void k_lin_mfma(const unsigned short* __restrict__ A,
                                                  const unsigned short* __restrict__ Bt,
                                                  const float* __restrict__ bias,
                                                  const float* __restrict__ emb,
                                                  const int* __restrict__ an,
                                                  const float* __restrict__ outw,
                                                  const float* __restrict__ u1,
                                                  const float* __restrict__ yacc,
                                                  float* __restrict__ out, int M)
{
    __shared__ unsigned short As[GBM][LDK];
    __shared__ unsigned short Bs[GBN][LDK];
    int t = threadIdx.x;
    int wave = t >> 6, lane = t & 63;
    int wr = wave >> 1, wc = wave & 1;
    int l15 = lane & 15, l16 = lane >> 4;
    int bm = blockIdx.y * GBM, bn = blockIdx.x * GBN;
    f32x4 acc[4][4] = {};
    for (int k0 = 0; k0 < DF; k0 += GBK) {
        #pragma unroll
        for (int i = 0; i < 2; i++) {
            int c = t + i*256;
            int row = c >> 2, ko = (c & 3) * 8;
            int4v av = *(const int4v*)&A[(size_t)(bm + row)*DF + k0 + ko];
            int4v bv = *(const int4v*)&Bt[(size_t)(bn + row)*DF + k0 + ko];
            *(int4v*)&As[row][ko] = av;
            *(int4v*)&Bs[row][ko] = bv;
        }
        __syncthreads();
        bf16x8 af[4], bfr[4];
        #pragma unroll
        for (int m = 0; m < 4; m++)
            af[m] = *(const bf16x8*)&As[wr*64 + m*16 + l15][l16*8];
        #pragma unroll
        for (int n = 0; n < 4; n++)
            bfr[n] = *(const bf16x8*)&Bs[wc*64 + n*16 + l15][l16*8];
        #pragma unroll
        for (int m = 0; m < 4; m++)
            #pragma unroll
            for (int n = 0; n < 4; n++)
                acc[m][n] = __builtin_amdgcn_mfma_f32_16x16x32_bf16(af[m], bfr[n], acc[m][n], 0, 0, 0);
        __syncthreads();
    }
    float epart = 0.0f;
    int crow0 = bm + wr*64, ccol0 = bn + wc*64;
    float ow4[4], u14[4], b4[4];
    #pragma unroll
    for (int n = 0; n < 4; n++) {
        int col = ccol0 + n*16 + l15;
        ow4[n] = outw[col];
        u14[n] = u1[col];
        b4[n]  = bias[col];
    }
    #pragma unroll
    for (int m = 0; m < 4; m++) {
        #pragma unroll
        for (int j = 0; j < 4; j++) {
            int row = crow0 + m*16 + l16*4 + j;
            if (row < M) {
                int a = an[row];
                float yv = yacc[(size_t)row*16 + l15];
                #pragma unroll
                for (int n = 0; n < 4; n++) {
                    int col = ccol0 + n*16 + l15;
                    float v = acc[m][n][j] + emb[(size_t)a*DF + col] + b4[n];
                    epart += v * (ow4[n] + u14[n] * yv);
                }
            }
        }
    }
    __shared__ float red[256];
    red[t] = epart;
    __syncthreads();
    for (int s = 128; s > 0; s >>= 1) {
        if (t < s) red[t] += red[t + s];
        __syncthreads();
    }
    if (t == 0) atomicAdd(out, red[0]);
}

// K_pre: u1 and constant-bias energy term
__global__ __launch_bounds__(512) void k_pre(const float* __restrict__ lw1,
                                             const float* __restrict__ tw1,
                                             const float* __restrict__ lb1,
                                             const float* __restrict__ ow,
                                             const float* __restrict__ ob,
                                             float* __restrict__ u1,
                                             float* __restrict__ out, int N)
{
    __shared__ float v[DF];
    __shared__ float ows[DF];
    __shared__ float red[DF];
    int t = threadIdx.x;
    ows[t] = ow[t];
    __syncthreads();
    float acc = 0.0f;
    for (int k = 0; k < DF; k++) acc += lw1[(size_t)t*DF + k] * ows[k];
    v[t] = acc;
    __syncthreads();
    int c = t >> 4, m = t & 15, l = c_lidx[m];
    float u = 0.0f;
    #pragma unroll
    for (int d = 0; d < 32; d++) u += tw1[l*1024 + c*32 + d] * v[d*16 + m];
    u1[t] = u;
    red[t] = lb1[t] * ows[t];
    __syncthreads();
    for (int s = 256; s > 0; s >>= 1) {
        if (t < s) red[t] += red[t + s];
        __syncthreads();
    }
    if (t == 0) out[0] += (float)N * (red[0] + ob[0]);
}

extern "C" void kernel_launch(void* const* d_in, const int* in_sizes, int n_in,
                              void* d_out, int out_size, void* d_ws, size_t ws_size,
                              hipStream_t stream)
{
    const float* pos  = (const float*)d_in[0];
    const float* cell = (const float*)d_in[1];
    const int*   an   = (const int*)d_in[2];
    const int*   ei   = (const int*)d_in[3];
    const float* emb  = (const float*)d_in[4];
    const float* tw0  = (const float*)d_in[5];
    const float* lw0  = (const float*)d_in[6];
    const float* lb0  = (const float*)d_in[7];
    const float* tw1  = (const float*)d_in[8];
    const float* lw1  = (const float*)d_in[9];
    const float* lb1  = (const float*)d_in[10];
    const float* ow   = (const float*)d_in[11];
    const float* ob   = (const float*)d_in[12];
    int N  = in_sizes[0] / 3;
    int E  = in_sizes[3] / 2;
    int NE = in_sizes[4] / DF;   // 89 elements
    const int* src = ei;
    const int* dst = ei + E;
    int Mpad = ((N + GBM - 1) / GBM) * GBM;

    char* ws = (char*)d_ws;
    size_t off = 0;
    auto alloc = [&](size_t bytes) { void* p = ws + off; off += (bytes + 255) / 256 * 256; return p; };

    float* Y              = (float*)alloc((size_t)E * 16 * 4);
    int*   eA             = (int*)alloc((size_t)E * 4);
    int*   aA             = (int*)alloc((size_t)E * 4);
    unsigned short* tfe   = (unsigned short*)alloc((size_t)NE * DF * 2);
    unsigned short* aggbf = (unsigned short*)alloc((size_t)Mpad * DF * 2);
    unsigned short* Bt    = (unsigned short*)alloc((size_t)DF * DF * 2);
    float* u1   = (float*)alloc(DF * 4);
    float* yacc = (float*)alloc((size_t)N * 16 * 4);
    int*   cnt  = (int*)alloc((size_t)N * 4);
    int*   rp   = (int*)alloc((size_t)(N + 1) * 4);

    float* out = (float*)d_out;

    hipMemsetAsync(out, 0, sizeof(float), stream);
    hipMemsetAsync(cnt, 0, (size_t)N * 4, stream);
    hipMemsetAsync(yacc, 0, (size_t)N * 16 * 4, stream);
    if (Mpad > N)
        hipMemsetAsync(aggbf + (size_t)N * DF, 0, (size_t)(Mpad - N) * DF * 2, stream);

    k_pre<<<1, 512, 0, stream>>>(lw1, tw1, lb1, ow, ob, u1, out, N);
    k_edge_sh<<<(E + 255) / 256, 256, 0, stream>>>(pos, src, dst, cell, Y, yacc, cnt, E);
    k_scan<<<1, 1024, 0, stream>>>(cnt, rp, N, E);
    k_fill<<<(E + 255) / 256, 256, 0, stream>>>(src, dst, an, cnt, eA, aA, E);
    k_convb<<<(DF * DF) / 256, 256, 0, stream>>>(lw0, Bt);
    k_tf_elem<<<NE, 256, 0, stream>>>(emb, tw0, tfe, NE);
    k_agg<<<(N + 3) / 4, 256, 0, stream>>>(tfe, Y, rp, eA, aA, aggbf, N);
    dim3 g4(DF / GBN, (Mpad + GBM - 1) / GBM);
    k_lin_mfma<<<g4, 256, 0, stream>>>(aggbf, Bt, lb0, emb, an, ow, u1, yacc, out, N);
}

// Round 5
// 185.533 us; speedup vs baseline: 2.0615x; 2.0615x over previous
//
#include <hip/hip_runtime.h>
#include <math.h>

#define DF 512

typedef __attribute__((ext_vector_type(8))) short bf16x8;
typedef __attribute__((ext_vector_type(4))) float f32x4;
typedef __attribute__((ext_vector_type(4))) int int4v;

__device__ __constant__ int c_lidx[16] = {0,1,1,1,2,2,2,2,2,3,3,3,3,3,3,3};

__device__ inline float bf2f(unsigned short s) {
    union { unsigned int u; float f; } x;
    x.u = ((unsigned int)s) << 16;
    return x.f;
}
__device__ inline unsigned short f2bf(float f) {
    union { float f; unsigned int u; } x; x.f = f;
    unsigned int r = x.u + 0x7fffu + ((x.u >> 16) & 1u);
    return (unsigned short)(r >> 16);
}

// K1: per-edge spherical harmonics Y[E][16] + dst-histogram (1 atomic/edge)
__global__ void k_edge_sh(const float* __restrict__ pos,
                          const int* __restrict__ src,
                          const int* __restrict__ dst,
                          const float* __restrict__ cell,
                          float* __restrict__ Y,
                          int* __restrict__ cnt, int E)
{
    int e = blockIdx.x * blockDim.x + threadIdx.x;
    if (e >= E) return;
    int s = src[e], d = dst[e];
    float cx = cell[0], cy = cell[4], cz = cell[8];
    float ex = pos[d*3+0] - pos[s*3+0];
    float ey = pos[d*3+1] - pos[s*3+1];
    float ez = pos[d*3+2] - pos[s*3+2];
    ex -= rintf(ex/cx)*cx;
    ey -= rintf(ey/cy)*cy;
    ez -= rintf(ez/cz)*cz;
    float len = fmaxf(sqrtf(ex*ex + ey*ey + ez*ez), 1e-8f);
    float x = ex/len, y = ey/len, z = ez/len;
    float x2 = x*x, y2 = y*y, z2 = z*z;
    float o[16];
    o[0]  = 0.28209479177387814f;
    o[1]  = 0.4886025119029199f*y;
    o[2]  = 0.4886025119029199f*z;
    o[3]  = 0.4886025119029199f*x;
    o[4]  = 1.0925484305920792f*x*y;
    o[5]  = 1.0925484305920792f*y*z;
    o[6]  = 0.31539156525252005f*(3.0f*z2 - 1.0f);
    o[7]  = 1.0925484305920792f*x*z;
    o[8]  = 0.5462742152960396f*(x2 - y2);
    o[9]  = 0.5900435899266435f*y*(3.0f*x2 - y2);
    o[10] = 2.890611442640554f*x*y*z;
    o[11] = 0.4570457994644658f*y*(5.0f*z2 - 1.0f);
    o[12] = 0.3731763325901154f*z*(5.0f*z2 - 3.0f);
    o[13] = 0.4570457994644658f*x*(5.0f*z2 - 1.0f);
    o[14] = 1.445305721320277f*z*(x2 - y2);
    o[15] = 0.5900435899266435f*x*(x2 - 3.0f*y2);
    float4* Yo = (float4*)(Y + (size_t)e*16);
    Yo[0] = make_float4(o[0],o[1],o[2],o[3]);
    Yo[1] = make_float4(o[4],o[5],o[6],o[7]);
    Yo[2] = make_float4(o[8],o[9],o[10],o[11]);
    Yo[3] = make_float4(o[12],o[13],o[14],o[15]);
    atomicAdd(&cnt[d], 1);
}

// K2: per-ELEMENT tensor-product: tfe[a, d*16+m] = bf16( sum_c emb[a][c*16+m] * W0[l(m)][c][d] )
__global__ __launch_bounds__(256) void k_tf_elem(const float* __restrict__ emb,
                                                 const float* __restrict__ w0,
                                                 unsigned short* __restrict__ tfe, int NE)
{
    __shared__ float nf[DF];
    __shared__ float w[4*32*32];
    int a = blockIdx.x;
    int t = threadIdx.x;
    nf[t]       = emb[(size_t)a*DF + t];
    nf[t + 256] = emb[(size_t)a*DF + t + 256];
    for (int i = t; i < 4096; i += 256) w[i] = w0[i];
    __syncthreads();
    #pragma unroll
    for (int rep = 0; rep < 2; rep++) {
        int f = t + rep*256;
        int d = f >> 4, m = f & 15;
        int l = c_lidx[m];
        const float* wl = &w[l*1024 + d];
        float acc = 0.0f;
        #pragma unroll
        for (int c = 0; c < 32; c++) acc += nf[c*16 + m] * wl[c*32];
        tfe[(size_t)a*DF + f] = f2bf(acc);
    }
}

// single-block exclusive scan (4 elems/thread): cnt[0..N) -> rp[0..N]; cnt becomes cursor
__global__ __launch_bounds__(1024) void k_scan(int* __restrict__ cnt,
                                               int* __restrict__ rp, int N, int E)
{
    __shared__ int wsum[16];
    __shared__ int sh_total;
    __shared__ int sh_carry;
    int t = threadIdx.x;
    int lane = t & 63, wv = t >> 6;
    if (t == 0) sh_carry = 0;
    __syncthreads();
    for (int base = 0; base < N; base += 4096) {
        int i0 = base + t*4;
        int v0 = (i0+0 < N) ? cnt[i0+0] : 0;
        int v1 = (i0+1 < N) ? cnt[i0+1] : 0;
        int v2 = (i0+2 < N) ? cnt[i0+2] : 0;
        int v3 = (i0+3 < N) ? cnt[i0+3] : 0;
        int s0 = v0, s1 = s0+v1, s2 = s1+v2, tot = s2+v3;
        int v = tot;
        #pragma unroll
        for (int off = 1; off < 64; off <<= 1) {
            int x = __shfl_up(v, off, 64);
            if (lane >= off) v += x;
        }
        if (lane == 63) wsum[wv] = v;
        __syncthreads();
        if (t < 16) {
            int x = wsum[t];
            int incl = x;
            #pragma unroll
            for (int off = 1; off < 16; off <<= 1) {
                int y = __shfl_up(incl, off, 16);
                if (t >= off) incl += y;
            }
            wsum[t] = incl - x;
            if (t == 15) sh_total = incl;
        }
        __syncthreads();
        int excl = sh_carry + wsum[wv] + (v - tot);
        if (i0+0 < N) { rp[i0+0] = excl;      cnt[i0+0] = excl; }
        if (i0+1 < N) { rp[i0+1] = excl + s0; cnt[i0+1] = excl + s0; }
        if (i0+2 < N) { rp[i0+2] = excl + s1; cnt[i0+2] = excl + s1; }
        if (i0+3 < N) { rp[i0+3] = excl + s2; cnt[i0+3] = excl + s2; }
        __syncthreads();
        if (t == 0) sh_carry += sh_total;
        __syncthreads();
    }
    if (t == 0) rp[N] = E;
}

// fill CSR: Yp[p] = Y[e] (64B row, CSR order), aA[p] = element of src node
__global__ void k_fill(const int* __restrict__ src, const int* __restrict__ dst,
                       const int* __restrict__ an,
                       const float* __restrict__ Y,
                       int* __restrict__ cur,
                       float* __restrict__ Yp,
                       int* __restrict__ aA, int E)
{
    int e = blockIdx.x * blockDim.x + threadIdx.x;
    if (e >= E) return;
    int d = dst[e];
    int p = atomicAdd(&cur[d], 1);
    const float4* yi = (const float4*)(Y + (size_t)e*16);
    float4 y0 = yi[0], y1 = yi[1], y2 = yi[2], y3 = yi[3];
    float4* yo = (float4*)(Yp + (size_t)p*16);
    yo[0] = y0; yo[1] = y1; yo[2] = y2; yo[3] = y3;
    aA[p] = an[src[e]];
}

// K5a: yacc[n, m] = sum_{e: src[e]=n} Y[e, m]  (one independent atomic per thread)
__global__ void k_yacc(const float* __restrict__ Y, const int* __restrict__ src,
                       float* __restrict__ yacc, int E)
{
    int g = blockIdx.x * blockDim.x + threadIdx.x;
    if (g >= E * 16) return;
    int e = g >> 4, m = g & 15;
    atomicAdd(&yacc[(size_t)src[e]*16 + m], Y[g]);
}

// K3: CSR aggregation, one wave per destination node; Yp/aA sequential.
// aggbf[n, f] = bf16( sum_i Yp[i, f&15] * tfe[aA[i], f] )
__device__ inline void agg_edge(const unsigned short* __restrict__ tfe,
                                const float* __restrict__ Yp,
                                int i, int a, int f0, int yoff, float* acc)
{
    bf16x8 v = *(const bf16x8*)(tfe + (size_t)a*DF + f0);
    const float4* q = (const float4*)(Yp + (size_t)i*16 + yoff);
    float4 y0 = q[0], y1 = q[1];
    acc[0] += bf2f((unsigned short)v[0])*y0.x;
    acc[1] += bf2f((unsigned short)v[1])*y0.y;
    acc[2] += bf2f((unsigned short)v[2])*y0.z;
    acc[3] += bf2f((unsigned short)v[3])*y0.w;
    acc[4] += bf2f((unsigned short)v[4])*y1.x;
    acc[5] += bf2f((unsigned short)v[5])*y1.y;
    acc[6] += bf2f((unsigned short)v[6])*y1.z;
    acc[7] += bf2f((unsigned short)v[7])*y1.w;
}

__global__ __launch_bounds__(256) void k_agg(const unsigned short* __restrict__ tfe,
                                             const float* __restrict__ Yp,
                                             const int* __restrict__ rp,
                                             const int* __restrict__ aA,
                                             unsigned short* __restrict__ aggbf, int N)
{
    int wid = blockIdx.x * 4 + (threadIdx.x >> 6);
    if (wid >= N) return;
    int lane = threadIdx.x & 63;
    int f0 = lane * 8;
    int yoff = f0 & 15;
    int beg = rp[wid], end = rp[wid + 1];
    float acc[8] = {0,0,0,0,0,0,0,0};
    int i = beg;
    for (; i + 1 < end; i += 2) {
        agg_edge(tfe, Yp, i,   aA[i],   f0, yoff, acc);
        agg_edge(tfe, Yp, i+1, aA[i+1], f0, yoff, acc);
    }
    if (i < end) agg_edge(tfe, Yp, i, aA[i], f0, yoff, acc);
    bf16x8 o;
    #pragma unroll
    for (int j = 0; j < 8; j++) o[j] = (short)f2bf(acc[j]);
    *(bf16x8*)(aggbf + (size_t)wid*DF + f0) = o;
}

// Bt[n][k] = bf16(lin_w0[k][n])
__global__ void k_convb(const float* __restrict__ w, unsigned short* __restrict__ bt)
{
    int idx = blockIdx.x * 256 + threadIdx.x;
    int n = idx >> 9, k = idx & 511;
    bt[idx] = f2bf(w[(size_t)k*DF + n]);
}

// K4: MFMA GEMM, fully-fused epilogue:
// out += sum_{row,col} (A@B + emb[an] + bias)[row,col] * (outw[col] + u1[col]*yacc[row,col&15])
#define GBM 128
#define GBN 128
#define GBK 32
#define LDK 40
__global__ __launch_bounds__(256) void k_lin_mfma(const unsigned short* __restrict__ A,
                                                  const unsigned short* __restrict__ Bt,
                                                  const float* __restrict__ bias,
                                                  const float* __restrict__ emb,
                                                  const int* __restrict__ an,
                                                  const float* __restrict__ outw,
                                                  const float* __restrict__ u1,
                                                  const float* __restrict__ yacc,
                                                  float* __restrict__ out, int M)
{
    __shared__ unsigned short As[GBM][LDK];
    __shared__ unsigned short Bs[GBN][LDK];
    int t = threadIdx.x;
    int wave = t >> 6, lane = t & 63;
    int wr = wave >> 1, wc = wave & 1;
    int l15 = lane & 15, l16 = lane >> 4;
    int bm = blockIdx.y * GBM, bn = blockIdx.x * GBN;
    f32x4 acc[4][4] = {};
    for (int k0 = 0; k0 < DF; k0 += GBK) {
        #pragma unroll
        for (int i = 0; i < 2; i++) {
            int c = t + i*256;
            int row = c >> 2, ko = (c & 3) * 8;
            int4v av = *(const int4v*)&A[(size_t)(bm + row)*DF + k0 + ko];
            int4v bv = *(const int4v*)&Bt[(size_t)(bn + row)*DF + k0 + ko];
            *(int4v*)&As[row][ko] = av;
            *(int4v*)&Bs[row][ko] = bv;
        }
        __syncthreads();
        bf16x8 af[4], bfr[4];
        #pragma unroll
        for (int m = 0; m < 4; m++)
            af[m] = *(const bf16x8*)&As[wr*64 + m*16 + l15][l16*8];
        #pragma unroll
        for (int n = 0; n < 4; n++)
            bfr[n] = *(const bf16x8*)&Bs[wc*64 + n*16 + l15][l16*8];
        #pragma unroll
        for (int m = 0; m < 4; m++)
            #pragma unroll
            for (int n = 0; n < 4; n++)
                acc[m][n] = __builtin_amdgcn_mfma_f32_16x16x32_bf16(af[m], bfr[n], acc[m][n], 0, 0, 0);
        __syncthreads();
    }
    float epart = 0.0f;
    int crow0 = bm + wr*64, ccol0 = bn + wc*64;
    float ow4[4], u14[4], b4[4];
    #pragma unroll
    for (int n = 0; n < 4; n++) {
        int col = ccol0 + n*16 + l15;
        ow4[n] = outw[col];
        u14[n] = u1[col];
        b4[n]  = bias[col];
    }
    #pragma unroll
    for (int m = 0; m < 4; m++) {
        #pragma unroll
        for (int j = 0; j < 4; j++) {
            int row = crow0 + m*16 + l16*4 + j;
            if (row < M) {
                int a = an[row];
                float yv = yacc[(size_t)row*16 + l15];
                #pragma unroll
                for (int n = 0; n < 4; n++) {
                    int col = ccol0 + n*16 + l15;
                    float v = acc[m][n][j] + emb[(size_t)a*DF + col] + b4[n];
                    epart += v * (ow4[n] + u14[n] * yv);
                }
            }
        }
    }
    __shared__ float red[256];
    red[t] = epart;
    __syncthreads();
    for (int s = 128; s > 0; s >>= 1) {
        if (t < s) red[t] += red[t + s];
        __syncthreads();
    }
    if (t == 0) atomicAdd(out, red[0]);
}

// K_pre: u1 and constant-bias energy term
__global__ __launch_bounds__(512) void k_pre(const float* __restrict__ lw1,
                                             const float* __restrict__ tw1,
                                             const float* __restrict__ lb1,
                                             const float* __restrict__ ow,
                                             const float* __restrict__ ob,
                                             float* __restrict__ u1,
                                             float* __restrict__ out, int N)
{
    __shared__ float v[DF];
    __shared__ float ows[DF];
    __shared__ float red[DF];
    int t = threadIdx.x;
    ows[t] = ow[t];
    __syncthreads();
    float acc = 0.0f;
    for (int k = 0; k < DF; k++) acc += lw1[(size_t)t*DF + k] * ows[k];
    v[t] = acc;
    __syncthreads();
    int c = t >> 4, m = t & 15, l = c_lidx[m];
    float u = 0.0f;
    #pragma unroll
    for (int d = 0; d < 32; d++) u += tw1[l*1024 + c*32 + d] * v[d*16 + m];
    u1[t] = u;
    red[t] = lb1[t] * ows[t];
    __syncthreads();
    for (int s = 256; s > 0; s >>= 1) {
        if (t < s) red[t] += red[t + s];
        __syncthreads();
    }
    if (t == 0) out[0] += (float)N * (red[0] + ob[0]);
}

extern "C" void kernel_launch(void* const* d_in, const int* in_sizes, int n_in,
                              void* d_out, int out_size, void* d_ws, size_t ws_size,
                              hipStream_t stream)
{
    const float* pos  = (const float*)d_in[0];
    const float* cell = (const float*)d_in[1];
    const int*   an   = (const int*)d_in[2];
    const int*   ei   = (const int*)d_in[3];
    const float* emb  = (const float*)d_in[4];
    const float* tw0  = (const float*)d_in[5];
    const float* lw0  = (const float*)d_in[6];
    const float* lb0  = (const float*)d_in[7];
    const float* tw1  = (const float*)d_in[8];
    const float* lw1  = (const float*)d_in[9];
    const float* lb1  = (const float*)d_in[10];
    const float* ow   = (const float*)d_in[11];
    const float* ob   = (const float*)d_in[12];
    int N  = in_sizes[0] / 3;
    int E  = in_sizes[3] / 2;
    int NE = in_sizes[4] / DF;   // 89 elements
    const int* src = ei;
    const int* dst = ei + E;
    int Mpad = ((N + GBM - 1) / GBM) * GBM;

    char* ws = (char*)d_ws;
    size_t off = 0;
    auto alloc = [&](size_t bytes) { void* p = ws + off; off += (bytes + 255) / 256 * 256; return p; };

    float* Y              = (float*)alloc((size_t)E * 16 * 4);
    float* Yp             = (float*)alloc((size_t)E * 16 * 4);
    int*   aA             = (int*)alloc((size_t)E * 4);
    unsigned short* tfe   = (unsigned short*)alloc((size_t)NE * DF * 2);
    unsigned short* aggbf = (unsigned short*)alloc((size_t)Mpad * DF * 2);
    unsigned short* Bt    = (unsigned short*)alloc((size_t)DF * DF * 2);
    float* u1   = (float*)alloc(DF * 4);
    float* yacc = (float*)alloc((size_t)N * 16 * 4);
    int*   cnt  = (int*)alloc((size_t)N * 4);
    int*   rp   = (int*)alloc((size_t)(N + 1) * 4);

    float* out = (float*)d_out;

    hipMemsetAsync(out, 0, sizeof(float), stream);
    hipMemsetAsync(cnt, 0, (size_t)N * 4, stream);
    hipMemsetAsync(yacc, 0, (size_t)N * 16 * 4, stream);
    if (Mpad > N)
        hipMemsetAsync(aggbf + (size_t)N * DF, 0, (size_t)(Mpad - N) * DF * 2, stream);

    k_pre<<<1, 512, 0, stream>>>(lw1, tw1, lb1, ow, ob, u1, out, N);
    k_edge_sh<<<(E + 255) / 256, 256, 0, stream>>>(pos, src, dst, cell, Y, cnt, E);
    k_scan<<<1, 1024, 0, stream>>>(cnt, rp, N, E);
    k_fill<<<(E + 255) / 256, 256, 0, stream>>>(src, dst, an, Y, cnt, Yp, aA, E);
    k_convb<<<(DF * DF) / 256, 256, 0, stream>>>(lw0, Bt);
    k_tf_elem<<<NE, 256, 0, stream>>>(emb, tw0, tfe, NE);
    k_yacc<<<(E * 16 + 255) / 256, 256, 0, stream>>>(Y, src, yacc, E);
    k_agg<<<(N + 3) / 4, 256, 0, stream>>>(tfe, Yp, rp, aA, aggbf, N);
    dim3 g4(DF / GBN, (Mpad + GBM - 1) / GBM);
    k_lin_mfma<<<g4, 256, 0, stream>>>(aggbf, Bt, lb0, emb, an, ow, u1, yacc, out, N);
}

// Round 6
// 147.067 us; speedup vs baseline: 2.6007x; 1.2616x over previous
//
#include <hip/hip_runtime.h>
#include <math.h>

#define DF 512

typedef __attribute__((ext_vector_type(8))) short bf16x8;
typedef __attribute__((ext_vector_type(4))) float f32x4;
typedef __attribute__((ext_vector_type(4))) int int4v;

__device__ __constant__ int c_lidx[16] = {0,1,1,1,2,2,2,2,2,3,3,3,3,3,3,3};

__device__ inline float bf2f(unsigned short s) {
    union { unsigned int u; float f; } x;
    x.u = ((unsigned int)s) << 16;
    return x.f;
}
__device__ inline unsigned short f2bf(float f) {
    union { float f; unsigned int u; } x; x.f = f;
    unsigned int r = x.u + 0x7fffu + ((x.u >> 16) & 1u);
    return (unsigned short)(r >> 16);
}

// K0: one fused zero-fill (cnt, yacc, aggbf tail, out) — replaces 4 hipMemsetAsync
__global__ void k_zero(uint4* __restrict__ a, int na,
                       uint4* __restrict__ b, int nb,
                       uint4* __restrict__ c, int nc,
                       float* __restrict__ out)
{
    int i = blockIdx.x * blockDim.x + threadIdx.x;
    uint4 z = make_uint4(0, 0, 0, 0);
    if (i == 0) out[0] = 0.0f;
    if (i < na) { a[i] = z; return; }
    int j = i - na;
    if (j < nb) { b[j] = z; return; }
    int k = j - nb;
    if (k < nc) c[k] = z;
}

// K_pre-a: v[r] = dot(lw1[r,:], ow)  — one wave per row
__global__ __launch_bounds__(512) void k_matvec(const float* __restrict__ lw1,
                                                const float* __restrict__ ow,
                                                float* __restrict__ v)
{
    int r = blockIdx.x * 8 + (threadIdx.x >> 6);
    int lane = threadIdx.x & 63;
    const float* row = lw1 + (size_t)r * DF;
    float s = 0.0f;
    #pragma unroll
    for (int j = 0; j < 8; j++) s += row[lane + j*64] * ow[lane + j*64];
    #pragma unroll
    for (int off = 32; off > 0; off >>= 1) s += __shfl_xor(s, off, 64);
    if (lane == 0) v[r] = s;
}

// K_pre-b: u1[c*16+m] = sum_d tw1[l(m)][c][d]*v[d*16+m]; out += N*(lb1.ow + ob)
__global__ __launch_bounds__(512) void k_pre2(const float* __restrict__ tw1,
                                              const float* __restrict__ lb1,
                                              const float* __restrict__ ow,
                                              const float* __restrict__ ob,
                                              const float* __restrict__ v,
                                              float* __restrict__ u1,
                                              float* __restrict__ out, int N)
{
    __shared__ float vs[DF];
    __shared__ float red[DF];
    int t = threadIdx.x;
    vs[t] = v[t];
    red[t] = lb1[t] * ow[t];
    __syncthreads();
    int c = t >> 4, m = t & 15, l = c_lidx[m];
    float u = 0.0f;
    #pragma unroll
    for (int d = 0; d < 32; d++) u += tw1[l*1024 + c*32 + d] * vs[d*16 + m];
    u1[t] = u;
    __syncthreads();
    for (int s = 256; s > 0; s >>= 1) {
        if (t < s) red[t] += red[t + s];
        __syncthreads();
    }
    if (t == 0) atomicAdd(out, (float)N * (red[0] + ob[0]));
}

// K2: per-ELEMENT tensor-product: tfe[a, d*16+m] = bf16( sum_c emb[a][c*16+m] * W0[l(m)][c][d] )
__global__ __launch_bounds__(256) void k_tf_elem(const float* __restrict__ emb,
                                                 const float* __restrict__ w0,
                                                 unsigned short* __restrict__ tfe, int NE)
{
    __shared__ float nf[DF];
    __shared__ float w[4*32*32];
    int a = blockIdx.x;
    int t = threadIdx.x;
    nf[t]       = emb[(size_t)a*DF + t];
    nf[t + 256] = emb[(size_t)a*DF + t + 256];
    for (int i = t; i < 4096; i += 256) w[i] = w0[i];
    __syncthreads();
    #pragma unroll
    for (int rep = 0; rep < 2; rep++) {
        int f = t + rep*256;
        int d = f >> 4, m = f & 15;
        int l = c_lidx[m];
        const float* wl = &w[l*1024 + d];
        float acc = 0.0f;
        #pragma unroll
        for (int c = 0; c < 32; c++) acc += nf[c*16 + m] * wl[c*32];
        tfe[(size_t)a*DF + f] = f2bf(acc);
    }
}

// histogram of dst
__global__ void k_hist(const int* __restrict__ dst, int* __restrict__ cnt, int E)
{
    int e = blockIdx.x * blockDim.x + threadIdx.x;
    if (e < E) atomicAdd(&cnt[dst[e]], 1);
}

// single-block exclusive scan (4 elems/thread): cnt[0..N) -> rp[0..N]; cnt becomes cursor
__global__ __launch_bounds__(1024) void k_scan(int* __restrict__ cnt,
                                               int* __restrict__ rp, int N, int E)
{
    __shared__ int wsum[16];
    __shared__ int sh_total;
    __shared__ int sh_carry;
    int t = threadIdx.x;
    int lane = t & 63, wv = t >> 6;
    if (t == 0) sh_carry = 0;
    __syncthreads();
    for (int base = 0; base < N; base += 4096) {
        int i0 = base + t*4;
        int v0 = (i0+0 < N) ? cnt[i0+0] : 0;
        int v1 = (i0+1 < N) ? cnt[i0+1] : 0;
        int v2 = (i0+2 < N) ? cnt[i0+2] : 0;
        int v3 = (i0+3 < N) ? cnt[i0+3] : 0;
        int s0 = v0, s1 = s0+v1, s2 = s1+v2, tot = s2+v3;
        int v = tot;
        #pragma unroll
        for (int off = 1; off < 64; off <<= 1) {
            int x = __shfl_up(v, off, 64);
            if (lane >= off) v += x;
        }
        if (lane == 63) wsum[wv] = v;
        __syncthreads();
        if (t < 16) {
            int x = wsum[t];
            int incl = x;
            #pragma unroll
            for (int off = 1; off < 16; off <<= 1) {
                int y = __shfl_up(incl, off, 16);
                if (t >= off) incl += y;
            }
            wsum[t] = incl - x;
            if (t == 15) sh_total = incl;
        }
        __syncthreads();
        int excl = sh_carry + wsum[wv] + (v - tot);
        if (i0+0 < N) { rp[i0+0] = excl;      cnt[i0+0] = excl; }
        if (i0+1 < N) { rp[i0+1] = excl + s0; cnt[i0+1] = excl + s0; }
        if (i0+2 < N) { rp[i0+2] = excl + s1; cnt[i0+2] = excl + s1; }
        if (i0+3 < N) { rp[i0+3] = excl + s2; cnt[i0+3] = excl + s2; }
        __syncthreads();
        if (t == 0) sh_carry += sh_total;
        __syncthreads();
    }
    if (t == 0) rp[N] = E;
}

// K1': compute SH per edge, scatter directly into CSR slots: Yp[p], sA[p], aA[p]
__global__ void k_fill_sh(const float* __restrict__ pos,
                          const int* __restrict__ src,
                          const int* __restrict__ dst,
                          const int* __restrict__ an,
                          const float* __restrict__ cell,
                          int* __restrict__ cur,
                          float* __restrict__ Yp,
                          int* __restrict__ sA,
                          int* __restrict__ aA, int E)
{
    int e = blockIdx.x * blockDim.x + threadIdx.x;
    if (e >= E) return;
    int s = src[e], d = dst[e];
    float cx = cell[0], cy = cell[4], cz = cell[8];
    float ex = pos[d*3+0] - pos[s*3+0];
    float ey = pos[d*3+1] - pos[s*3+1];
    float ez = pos[d*3+2] - pos[s*3+2];
    ex -= rintf(ex/cx)*cx;
    ey -= rintf(ey/cy)*cy;
    ez -= rintf(ez/cz)*cz;
    float len = fmaxf(sqrtf(ex*ex + ey*ey + ez*ez), 1e-8f);
    float x = ex/len, y = ey/len, z = ez/len;
    float x2 = x*x, y2 = y*y, z2 = z*z;
    float o[16];
    o[0]  = 0.28209479177387814f;
    o[1]  = 0.4886025119029199f*y;
    o[2]  = 0.4886025119029199f*z;
    o[3]  = 0.4886025119029199f*x;
    o[4]  = 1.0925484305920792f*x*y;
    o[5]  = 1.0925484305920792f*y*z;
    o[6]  = 0.31539156525252005f*(3.0f*z2 - 1.0f);
    o[7]  = 1.0925484305920792f*x*z;
    o[8]  = 0.5462742152960396f*(x2 - y2);
    o[9]  = 0.5900435899266435f*y*(3.0f*x2 - y2);
    o[10] = 2.890611442640554f*x*y*z;
    o[11] = 0.4570457994644658f*y*(5.0f*z2 - 1.0f);
    o[12] = 0.3731763325901154f*z*(5.0f*z2 - 3.0f);
    o[13] = 0.4570457994644658f*x*(5.0f*z2 - 1.0f);
    o[14] = 1.445305721320277f*z*(x2 - y2);
    o[15] = 0.5900435899266435f*x*(x2 - 3.0f*y2);
    int p = atomicAdd(&cur[d], 1);
    float4* yo = (float4*)(Yp + (size_t)p*16);
    yo[0] = make_float4(o[0],o[1],o[2],o[3]);
    yo[1] = make_float4(o[4],o[5],o[6],o[7]);
    yo[2] = make_float4(o[8],o[9],o[10],o[11]);
    yo[3] = make_float4(o[12],o[13],o[14],o[15]);
    sA[p] = s;
    aA[p] = an[s];
}

// K5a: yacc[n, m] += Yp[p, m] for n = sA[p]  (one independent atomic per thread)
__global__ void k_yacc(const float* __restrict__ Yp, const int* __restrict__ sA,
                       float* __restrict__ yacc, int E)
{
    int g = blockIdx.x * blockDim.x + threadIdx.x;
    if (g >= E * 16) return;
    int p = g >> 4, m = g & 15;
    atomicAdd(&yacc[(size_t)sA[p]*16 + m], Yp[g]);
}

// K3: CSR aggregation, one wave per destination node; Yp/aA sequential.
__device__ inline void agg_edge(const unsigned short* __restrict__ tfe,
                                const float* __restrict__ Yp,
                                int i, int a, int f0, int yoff, float* acc)
{
    bf16x8 v = *(const bf16x8*)(tfe + (size_t)a*DF + f0);
    const float4* q = (const float4*)(Yp + (size_t)i*16 + yoff);
    float4 y0 = q[0], y1 = q[1];
    acc[0] += bf2f((unsigned short)v[0])*y0.x;
    acc[1] += bf2f((unsigned short)v[1])*y0.y;
    acc[2] += bf2f((unsigned short)v[2])*y0.z;
    acc[3] += bf2f((unsigned short)v[3])*y0.w;
    acc[4] += bf2f((unsigned short)v[4])*y1.x;
    acc[5] += bf2f((unsigned short)v[5])*y1.y;
    acc[6] += bf2f((unsigned short)v[6])*y1.z;
    acc[7] += bf2f((unsigned short)v[7])*y1.w;
}

__global__ __launch_bounds__(256) void k_agg(const unsigned short* __restrict__ tfe,
                                             const float* __restrict__ Yp,
                                             const int* __restrict__ rp,
                                             const int* __restrict__ aA,
                                             unsigned short* __restrict__ aggbf, int N)
{
    int wid = blockIdx.x * 4 + (threadIdx.x >> 6);
    if (wid >= N) return;
    int lane = threadIdx.x & 63;
    int f0 = lane * 8;
    int yoff = f0 & 15;
    int beg = rp[wid], end = rp[wid + 1];
    float acc[8] = {0,0,0,0,0,0,0,0};
    int i = beg;
    for (; i + 1 < end; i += 2) {
        agg_edge(tfe, Yp, i,   aA[i],   f0, yoff, acc);
        agg_edge(tfe, Yp, i+1, aA[i+1], f0, yoff, acc);
    }
    if (i < end) agg_edge(tfe, Yp, i, aA[i], f0, yoff, acc);
    bf16x8 o;
    #pragma unroll
    for (int j = 0; j < 8; j++) o[j] = (short)f2bf(acc[j]);
    *(bf16x8*)(aggbf + (size_t)wid*DF + f0) = o;
}

// Bt[n][k] = bf16(lin_w0[k][n])
__global__ void k_convb(const float* __restrict__ w, unsigned short* __restrict__ bt)
{
    int idx = blockIdx.x * 256 + threadIdx.x;
    int n = idx >> 9, k = idx & 511;
    bt[idx] = f2bf(w[(size_t)k*DF + n]);
}

// K4: MFMA GEMM, fully-fused epilogue:
// out += sum_{row,col} (A@B + emb[an] + bias)[row,col] * (outw[col] + u1[col]*yacc[row,col&15])
#define GBM 128
#define GBN 128
#define GBK 32
#define LDK 40
__global__ __launch_bounds__(256) void k_lin_mfma(const unsigned short* __restrict__ A,
                                                  const unsigned short* __restrict__ Bt,
                                                  const float* __restrict__ bias,
                                                  const float* __restrict__ emb,
                                                  const int* __restrict__ an,
                                                  const float* __restrict__ outw,
                                                  const float* __restrict__ u1,
                                                  const float* __restrict__ yacc,
                                                  float* __restrict__ out, int M)
{
    __shared__ unsigned short As[GBM][LDK];
    __shared__ unsigned short Bs[GBN][LDK];
    int t = threadIdx.x;
    int wave = t >> 6, lane = t & 63;
    int wr = wave >> 1, wc = wave & 1;
    int l15 = lane & 15, l16 = lane >> 4;
    int bm = blockIdx.y * GBM, bn = blockIdx.x * GBN;
    f32x4 acc[4][4] = {};
    for (int k0 = 0; k0 < DF; k0 += GBK) {
        #pragma unroll
        for (int i = 0; i < 2; i++) {
            int c = t + i*256;
            int row = c >> 2, ko = (c & 3) * 8;
            int4v av = *(const int4v*)&A[(size_t)(bm + row)*DF + k0 + ko];
            int4v bv = *(const int4v*)&Bt[(size_t)(bn + row)*DF + k0 + ko];
            *(int4v*)&As[row][ko] = av;
            *(int4v*)&Bs[row][ko] = bv;
        }
        __syncthreads();
        bf16x8 af[4], bfr[4];
        #pragma unroll
        for (int m = 0; m < 4; m++)
            af[m] = *(const bf16x8*)&As[wr*64 + m*16 + l15][l16*8];
        #pragma unroll
        for (int n = 0; n < 4; n++)
            bfr[n] = *(const bf16x8*)&Bs[wc*64 + n*16 + l15][l16*8];
        #pragma unroll
        for (int m = 0; m < 4; m++)
            #pragma unroll
            for (int n = 0; n < 4; n++)
                acc[m][n] = __builtin_amdgcn_mfma_f32_16x16x32_bf16(af[m], bfr[n], acc[m][n], 0, 0, 0);
        __syncthreads();
    }
    float epart = 0.0f;
    int crow0 = bm + wr*64, ccol0 = bn + wc*64;
    float ow4[4], u14[4], b4[4];
    #pragma unroll
    for (int n = 0; n < 4; n++) {
        int col = ccol0 + n*16 + l15;
        ow4[n] = outw[col];
        u14[n] = u1[col];
        b4[n]  = bias[col];
    }
    #pragma unroll
    for (int m = 0; m < 4; m++) {
        #pragma unroll
        for (int j = 0; j < 4; j++) {
            int row = crow0 + m*16 + l16*4 + j;
            if (row < M) {
                int a = an[row];
                float yv = yacc[(size_t)row*16 + l15];
                #pragma unroll
                for (int n = 0; n < 4; n++) {
                    int col = ccol0 + n*16 + l15;
                    float v = acc[m][n][j] + emb[(size_t)a*DF + col] + b4[n];
                    epart += v * (ow4[n] + u14[n] * yv);
                }
            }
        }
    }
    __shared__ float red[256];
    red[t] = epart;
    __syncthreads();
    for (int s = 128; s > 0; s >>= 1) {
        if (t < s) red[t] += red[t + s];
        __syncthreads();
    }
    if (t == 0) atomicAdd(out, red[0]);
}

extern "C" void kernel_launch(void* const* d_in, const int* in_sizes, int n_in,
                              void* d_out, int out_size, void* d_ws, size_t ws_size,
                              hipStream_t stream)
{
    const float* pos  = (const float*)d_in[0];
    const float* cell = (const float*)d_in[1];
    const int*   an   = (const int*)d_in[2];
    const int*   ei   = (const int*)d_in[3];
    const float* emb  = (const float*)d_in[4];
    const float* tw0  = (const float*)d_in[5];
    const float* lw0  = (const float*)d_in[6];
    const float* lb0  = (const float*)d_in[7];
    const float* tw1  = (const float*)d_in[8];
    const float* lw1  = (const float*)d_in[9];
    const float* lb1  = (const float*)d_in[10];
    const float* ow   = (const float*)d_in[11];
    const float* ob   = (const float*)d_in[12];
    int N  = in_sizes[0] / 3;
    int E  = in_sizes[3] / 2;
    int NE = in_sizes[4] / DF;   // 89 elements
    const int* src = ei;
    const int* dst = ei + E;
    int Mpad = ((N + GBM - 1) / GBM) * GBM;

    char* ws = (char*)d_ws;
    size_t off = 0;
    auto alloc = [&](size_t bytes) { void* p = ws + off; off += (bytes + 255) / 256 * 256; return p; };

    float* Yp             = (float*)alloc((size_t)E * 16 * 4);
    int*   sA             = (int*)alloc((size_t)E * 4);
    int*   aA             = (int*)alloc((size_t)E * 4);
    unsigned short* tfe   = (unsigned short*)alloc((size_t)NE * DF * 2);
    unsigned short* aggbf = (unsigned short*)alloc((size_t)Mpad * DF * 2);
    unsigned short* Bt    = (unsigned short*)alloc((size_t)DF * DF * 2);
    float* u1   = (float*)alloc(DF * 4);
    float* vtmp = (float*)alloc(DF * 4);
    float* yacc = (float*)alloc((size_t)N * 16 * 4);
    int*   cnt  = (int*)alloc((size_t)N * 4);
    int*   rp   = (int*)alloc((size_t)(N + 1) * 4);

    float* out = (float*)d_out;

    // fused zeroing: cnt (N*4 B), yacc (N*64 B), aggbf tail ((Mpad-N)*1024 B), out
    int na = (N * 4) / 16;
    int nb = (N * 64) / 16;
    int nc = ((Mpad - N) * DF * 2) / 16;
    int ztot = na + nb + nc;
    k_zero<<<(ztot + 255) / 256, 256, 0, stream>>>(
        (uint4*)cnt, na, (uint4*)yacc, nb,
        (uint4*)(aggbf + (size_t)N * DF), nc, out);

    k_matvec<<<DF / 8, 512, 0, stream>>>(lw1, ow, vtmp);
    k_pre2<<<1, 512, 0, stream>>>(tw1, lb1, ow, ob, vtmp, u1, out, N);
    k_hist<<<(E + 255) / 256, 256, 0, stream>>>(dst, cnt, E);
    k_scan<<<1, 1024, 0, stream>>>(cnt, rp, N, E);
    k_fill_sh<<<(E + 255) / 256, 256, 0, stream>>>(pos, src, dst, an, cell, cnt, Yp, sA, aA, E);
    k_convb<<<(DF * DF) / 256, 256, 0, stream>>>(lw0, Bt);
    k_tf_elem<<<NE, 256, 0, stream>>>(emb, tw0, tfe, NE);
    k_yacc<<<(E * 16 + 255) / 256, 256, 0, stream>>>(Yp, sA, yacc, E);
    k_agg<<<(N + 3) / 4, 256, 0, stream>>>(tfe, Yp, rp, aA, aggbf, N);
    dim3 g4(DF / GBN, (Mpad + GBM - 1) / GBM);
    k_lin_mfma<<<g4, 256, 0, stream>>>(aggbf, Bt, lb0, emb, an, ow, u1, yacc, out, N);
}